// Round 5
// baseline (440.055 us; speedup 1.0000x reference)
//
#include <hip/hip_runtime.h>
#include <hip/hip_bf16.h>

// DigitCaps dynamic routing, recompute-u_hat strategy. Output fp32.
// R5: parallelism round. R4 counters: agree 720 waves total (0.7/SIMD, occ 7%,
// VGPR 88 = spilled G[128]) and s_kernel 2880 waves. Restructure both to
// ~11.5k waves; alias u_part onto s_part to stay within proven ws footprint.
#define B 512
#define IC 1152
#define QD 8
#define OD 10
#define PD 16
#define NCS 36            // i-chunks for s split-K; 1152/36 = 32 i per chunk
#define CSI (IC / NCS)
#define NCB 16            // b-chunks for agreement kernel; 512/16 = 32 b per chunk
#define CSB (B / NCB)
#define SOP (B * OD * PD) // 81920 s/v elements

// c = softmax of zero bij = uniform 1/1152
__global__ __launch_bounds__(256) void init_c_kernel(float* __restrict__ c) {
  const int t = blockIdx.x * 256 + threadIdx.x;
  if (t < IC * OD) c[t] = 1.0f / (float)IC;
}

// s_part[chunk][b][o][p0..p0+3] = sum_{i in chunk} c[i,o]*sum_q W[i,o,p,q]x[b,i,q]
// block (64 b, 5 o-half), grid (B/64, 8, NCS); blockIdx.y = o-half | p-quarter<<1.
__global__ __launch_bounds__(320) void s_kernel(const float* __restrict__ x,
                                                const float* __restrict__ W,
                                                const float* __restrict__ c,
                                                float* __restrict__ s_part) {
  const int b = blockIdx.x * 64 + threadIdx.x;
  const int o = threadIdx.y + 5 * (blockIdx.y & 1);
  const int p0 = (blockIdx.y >> 1) * 4;  // p-quarter
  const int chunk = blockIdx.z;
  const int i0 = chunk * CSI;
  float acc[4] = {0.f, 0.f, 0.f, 0.f};
  for (int ii = 0; ii < CSI; ++ii) {
    const int i = i0 + ii;
    const int io = __builtin_amdgcn_readfirstlane(i * OD + o);  // wave-uniform
    const float ci = c[io];
    const float4* xp = (const float4*)(x + ((size_t)b * IC + i) * QD);
    const float4 xa = xp[0], xb = xp[1];
    const float4* wp = (const float4*)(W + (size_t)io * (PD * QD)) + 2 * p0;
#pragma unroll
    for (int pp = 0; pp < 4; ++pp) {
      const float4 w0 = wp[2 * pp], w1 = wp[2 * pp + 1];
      float d = w0.x * xa.x + w0.y * xa.y + w0.z * xa.z + w0.w * xa.w +
                w1.x * xb.x + w1.y * xb.y + w1.z * xb.z + w1.w * xb.w;
      acc[pp] = fmaf(ci, d, acc[pp]);
    }
  }
  float4* ov = (float4*)(s_part + ((size_t)chunk * B + b) * (OD * PD) + (size_t)o * PD + p0);
  ov[0] = make_float4(acc[0], acc[1], acc[2], acc[3]);
}

// reduce NCS partials (coalesced), squash per 16-lane p-group via shfl_xor.
__global__ __launch_bounds__(256) void squash_kernel(const float* __restrict__ s_part,
                                                     float* __restrict__ v,
                                                     float* __restrict__ out,
                                                     int write_out) {
  const int t = blockIdx.x * 256 + threadIdx.x;  // < 81920, layout (b*10+o)*16+p
  float sv = 0.f;
#pragma unroll
  for (int ch = 0; ch < NCS; ++ch) sv += s_part[(size_t)ch * SOP + t];
  float sq = sv * sv;
#pragma unroll
  for (int m = 1; m < 16; m <<= 1) sq += __shfl_xor(sq, m, 16);  // sum over p-group
  const float norm = sqrtf(sq + 1e-8f);
  const float val = sv * (sq / ((1.f + sq) * norm));
  v[t] = val;
  if (write_out) out[t] = val;
}

// u_part[chunk][i][o] = (1/B) sum_{b in chunk} sum_{q,p} W[i,o,p,q] x[b,i,q] v[b,o,p]
// lane = (i_local<<3)|q; block (64, 5), oo loop 2; grid (IC/8, NCB).
// Per-thread accumulator G[p] = sum_b x[b,i,q] v[b,o,p]: 16 regs, no spill.
__global__ __launch_bounds__(320) void agree_kernel(const float* __restrict__ x,
                                                    const float* __restrict__ W,
                                                    const float* __restrict__ v,
                                                    float* __restrict__ u_part) {
  const int il = threadIdx.x >> 3;
  const int q = threadIdx.x & 7;
  const int i = blockIdx.x * 8 + il;
  const int b0 = blockIdx.y * CSB;
#pragma unroll
  for (int oo = 0; oo < 2; ++oo) {
    const int o = threadIdx.y + 5 * oo;  // wave-uniform
    float G[PD];
#pragma unroll
    for (int p = 0; p < PD; ++p) G[p] = 0.f;
    for (int b = b0; b < b0 + CSB; ++b) {
      // one fully-coalesced 256B wave-load: 64 consecutive floats of x
      const float xbiq = x[((size_t)b * IC + i) * QD + q];
      // v row is wave-uniform -> scalar loads
      const int vofs = __builtin_amdgcn_readfirstlane((b * OD + o) * PD);
      const float4* vp = (const float4*)(v + vofs);
      const float4 v0 = vp[0], v1 = vp[1], v2 = vp[2], v3 = vp[3];
      const float vs[PD] = {v0.x, v0.y, v0.z, v0.w, v1.x, v1.y, v1.z, v1.w,
                            v2.x, v2.y, v2.z, v2.w, v3.x, v3.y, v3.z, v3.w};
#pragma unroll
      for (int p = 0; p < PD; ++p) G[p] = fmaf(xbiq, vs[p], G[p]);
    }
    // u_q = sum_p W[i,o,p,q] * G[p]; then reduce over the 8 q-lanes
    const float* wq = W + ((size_t)(i * OD + o) * PD) * QD + q;
    float u = 0.f;
#pragma unroll
    for (int p = 0; p < PD; ++p) u = fmaf(wq[(size_t)p * QD], G[p], u);
    u += __shfl_xor(u, 1);
    u += __shfl_xor(u, 2);
    u += __shfl_xor(u, 4);
    if (q == 0) u_part[((size_t)blockIdx.y * IC + i) * OD + o] = u * (1.0f / (float)B);
  }
}

// bij += sum_chunk u_part; c = softmax over i (axis 0). One block per o.
__global__ __launch_bounds__(256) void route_kernel(const float* __restrict__ u_part,
                                                    float* __restrict__ bij,
                                                    float* __restrict__ c,
                                                    int add_prev) {
  const int o = blockIdx.x;
  __shared__ float red[256];
  float val[5];
  float lmax = -1e30f;
#pragma unroll
  for (int k = 0; k < 5; ++k) {
    const int i = threadIdx.x + k * 256;
    if (i < IC) {
      float sacc = add_prev ? bij[i * OD + o] : 0.f;
#pragma unroll
      for (int ch = 0; ch < NCB; ++ch) sacc += u_part[((size_t)ch * IC + i) * OD + o];
      val[k] = sacc;
      bij[i * OD + o] = sacc;
      lmax = fmaxf(lmax, sacc);
    } else {
      val[k] = -1e30f;
    }
  }
  red[threadIdx.x] = lmax;
  __syncthreads();
  for (int st = 128; st > 0; st >>= 1) {
    if (threadIdx.x < st) red[threadIdx.x] = fmaxf(red[threadIdx.x], red[threadIdx.x + st]);
    __syncthreads();
  }
  const float gmax = red[0];
  __syncthreads();
  float lsum = 0.f;
#pragma unroll
  for (int k = 0; k < 5; ++k) {
    const int i = threadIdx.x + k * 256;
    if (i < IC) {
      val[k] = __expf(val[k] - gmax);
      lsum += val[k];
    }
  }
  red[threadIdx.x] = lsum;
  __syncthreads();
  for (int st = 128; st > 0; st >>= 1) {
    if (threadIdx.x < st) red[threadIdx.x] += red[threadIdx.x + st];
    __syncthreads();
  }
  const float inv = 1.f / red[0];
#pragma unroll
  for (int k = 0; k < 5; ++k) {
    const int i = threadIdx.x + k * 256;
    if (i < IC) c[i * OD + o] = val[k] * inv;
  }
}

extern "C" void kernel_launch(void* const* d_in, const int* in_sizes, int n_in,
                              void* d_out, int out_size, void* d_ws, size_t ws_size,
                              hipStream_t stream) {
  const float* x = (const float*)d_in[0];  // [512,1152,8] fp32
  const float* W = (const float*)d_in[1];  // [1152,10,16,8] fp32
  float* out = (float*)d_out;              // [512,10,16] fp32

  // workspace (fp32), 12.2 MB total (< 12.58 MB footprint proven in R1/R2).
  // u_part ALIASES s_part: s_part lifetime ends at squash, u_part's spans
  // agree->route, strictly between squash and the next s_kernel.
  float* ws = (float*)d_ws;
  float* s_part = ws;                      // NCS * 81920 = 2,949,120
  float* u_part = ws;                      // NCB * 11520 = 184,320 (alias, disjoint lifetime)
  float* v = s_part + (size_t)NCS * SOP;   // 81920
  float* bij = v + SOP;                    // 11520
  float* c = bij + IC * OD;                // 11520

  const dim3 sgrid(B / 64, 8, NCS), sblk(64, 5);
  const dim3 agrid(IC / 8, NCB), ablk(64, 5);

  init_c_kernel<<<(IC * OD + 255) / 256, 256, 0, stream>>>(c);
  for (int iter = 0; iter < 3; ++iter) {
    s_kernel<<<sgrid, sblk, 0, stream>>>(x, W, c, s_part);
    squash_kernel<<<SOP / 256, 256, 0, stream>>>(s_part, v, out, iter == 2);
    if (iter < 2) {
      agree_kernel<<<agrid, ablk, 0, stream>>>(x, W, v, u_part);
      route_kernel<<<OD, 256, 0, stream>>>(u_part, bij, c, iter > 0);
    }
  }
}

// Round 6
// 405.458 us; speedup vs baseline: 1.0853x; 1.0853x over previous
//
#include <hip/hip_runtime.h>
#include <hip/hip_bf16.h>

// DigitCaps dynamic routing, recompute-u_hat strategy. Output fp32.
// R6: s_kernel rebuilt — R5 counters showed its x loads were 64-line scatter
// (lane=b, rows 36KB apart): FETCH 55.7MB, VALUBusy 13%, everything idle.
// Now: coalesced global->LDS staging of x (transposed, pad-65 = conflict-free
// hot reads), wave-uniform W/c via SGPR, 72 FMA per i per thread, 5760 waves.
#define B 512
#define IC 1152
#define QD 8
#define OD 10
#define PD 16
#define NCS 36            // i-chunks for s split-K; 1152/36 = 32 i per chunk
#define CSI (IC / NCS)
#define IT 8              // i-subtile staged in LDS per round (4 rounds/chunk)
#define NCB 16            // b-chunks for agreement kernel; 512/16 = 32 b per chunk
#define CSB (B / NCB)
#define SOP (B * OD * PD) // 81920 s/v elements

// c = softmax of zero bij = uniform 1/1152
__global__ __launch_bounds__(256) void init_c_kernel(float* __restrict__ c) {
  const int t = blockIdx.x * 256 + threadIdx.x;
  if (t < IC * OD) c[t] = 1.0f / (float)IC;
}

// s_part[chunk][b][o][p0..p0+7] = sum_{i in chunk} c[i,o]*sum_q W[i,o,p,q]x[b,i,q]
// block (64 b-lanes, 5 o), grid (B/64, 4, NCS); blockIdx.y = ohalf | phalf<<1.
__global__ __launch_bounds__(320) void s_kernel(const float* __restrict__ x,
                                                const float* __restrict__ W,
                                                const float* __restrict__ c,
                                                float* __restrict__ s_part) {
  __shared__ float xT[IT * QD][64 + 1];  // [64 iq][65] — lane=b reads bank-free
  const int lane = threadIdx.x;          // b within tile
  const int b0 = blockIdx.x * 64;
  const int o = threadIdx.y + 5 * (blockIdx.y & 1);
  const int p0 = (blockIdx.y >> 1) * 8;
  const int chunk = blockIdx.z;
  const int tid = threadIdx.y * 64 + threadIdx.x;
  float acc[8] = {0.f, 0.f, 0.f, 0.f, 0.f, 0.f, 0.f, 0.f};

  for (int st = 0; st < CSI / IT; ++st) {
    const int i0 = chunk * CSI + st * IT;
    // stage 64 b-rows x[b][i0..i0+7][0..7] (64 contiguous floats each), coalesced
    for (int idx = tid; idx < 64 * 16; idx += 320) {
      const int bb = idx >> 4, f4 = idx & 15;
      const float4 val = *(const float4*)(x + ((size_t)(b0 + bb) * IC + i0) * QD + 4 * f4);
      xT[4 * f4 + 0][bb] = val.x;
      xT[4 * f4 + 1][bb] = val.y;
      xT[4 * f4 + 2][bb] = val.z;
      xT[4 * f4 + 3][bb] = val.w;
    }
    __syncthreads();
#pragma unroll
    for (int ii = 0; ii < IT; ++ii) {
      const int i = i0 + ii;
      const int io = __builtin_amdgcn_readfirstlane(i * OD + o);  // wave-uniform
      const float ci = c[io];
      const float* wrow = W + (size_t)io * (PD * QD) + p0 * QD;   // scalar loads
      float xv[QD];
#pragma unroll
      for (int q = 0; q < QD; ++q) xv[q] = xT[ii * QD + q][lane];
#pragma unroll
      for (int pp = 0; pp < 8; ++pp) {
        const float4 w0 = ((const float4*)(wrow + pp * QD))[0];
        const float4 w1 = ((const float4*)(wrow + pp * QD))[1];
        float d = w0.x * xv[0] + w0.y * xv[1] + w0.z * xv[2] + w0.w * xv[3] +
                  w1.x * xv[4] + w1.y * xv[5] + w1.z * xv[6] + w1.w * xv[7];
        acc[pp] = fmaf(ci, d, acc[pp]);
      }
    }
    __syncthreads();
  }
  float4* ov = (float4*)(s_part + ((size_t)chunk * B + b0 + lane) * (OD * PD) +
                         (size_t)o * PD + p0);
  ov[0] = make_float4(acc[0], acc[1], acc[2], acc[3]);
  ov[1] = make_float4(acc[4], acc[5], acc[6], acc[7]);
}

// reduce NCS partials (coalesced), squash per 16-lane p-group via shfl_xor.
__global__ __launch_bounds__(256) void squash_kernel(const float* __restrict__ s_part,
                                                     float* __restrict__ v,
                                                     float* __restrict__ out,
                                                     int write_out) {
  const int t = blockIdx.x * 256 + threadIdx.x;  // < 81920, layout (b*10+o)*16+p
  float sv = 0.f;
#pragma unroll
  for (int ch = 0; ch < NCS; ++ch) sv += s_part[(size_t)ch * SOP + t];
  float sq = sv * sv;
#pragma unroll
  for (int m = 1; m < 16; m <<= 1) sq += __shfl_xor(sq, m, 16);  // sum over p-group
  const float norm = sqrtf(sq + 1e-8f);
  const float val = sv * (sq / ((1.f + sq) * norm));
  v[t] = val;
  if (write_out) out[t] = val;
}

// u_part[chunk][i][o] = (1/B) sum_{b in chunk} sum_{q,p} W[i,o,p,q] x[b,i,q] v[b,o,p]
// lane = (i_local<<3)|q; block (64, 5), oo loop 2; grid (IC/8, NCB).
__global__ __launch_bounds__(320) void agree_kernel(const float* __restrict__ x,
                                                    const float* __restrict__ W,
                                                    const float* __restrict__ v,
                                                    float* __restrict__ u_part) {
  const int il = threadIdx.x >> 3;
  const int q = threadIdx.x & 7;
  const int i = blockIdx.x * 8 + il;
  const int b0 = blockIdx.y * CSB;
#pragma unroll
  for (int oo = 0; oo < 2; ++oo) {
    const int o = threadIdx.y + 5 * oo;  // wave-uniform
    float G[PD];
#pragma unroll
    for (int p = 0; p < PD; ++p) G[p] = 0.f;
    for (int b = b0; b < b0 + CSB; b += 2) {  // 2-way unroll for MLP
      const float xa = x[((size_t)b * IC + i) * QD + q];
      const float xc = x[((size_t)(b + 1) * IC + i) * QD + q];
      const int vo0 = __builtin_amdgcn_readfirstlane((b * OD + o) * PD);
      const int vo1 = __builtin_amdgcn_readfirstlane(((b + 1) * OD + o) * PD);
      const float4* vp0 = (const float4*)(v + vo0);
      const float4* vp1 = (const float4*)(v + vo1);
      const float4 a0 = vp0[0], a1 = vp0[1], a2 = vp0[2], a3 = vp0[3];
      const float4 c0 = vp1[0], c1 = vp1[1], c2 = vp1[2], c3 = vp1[3];
      const float va[PD] = {a0.x, a0.y, a0.z, a0.w, a1.x, a1.y, a1.z, a1.w,
                            a2.x, a2.y, a2.z, a2.w, a3.x, a3.y, a3.z, a3.w};
      const float vc[PD] = {c0.x, c0.y, c0.z, c0.w, c1.x, c1.y, c1.z, c1.w,
                            c2.x, c2.y, c2.z, c2.w, c3.x, c3.y, c3.z, c3.w};
#pragma unroll
      for (int p = 0; p < PD; ++p) G[p] = fmaf(xa, va[p], G[p]);
#pragma unroll
      for (int p = 0; p < PD; ++p) G[p] = fmaf(xc, vc[p], G[p]);
    }
    const float* wq = W + ((size_t)(i * OD + o) * PD) * QD + q;
    float u = 0.f;
#pragma unroll
    for (int p = 0; p < PD; ++p) u = fmaf(wq[(size_t)p * QD], G[p], u);
    u += __shfl_xor(u, 1);
    u += __shfl_xor(u, 2);
    u += __shfl_xor(u, 4);
    if (q == 0) u_part[((size_t)blockIdx.y * IC + i) * OD + o] = u * (1.0f / (float)B);
  }
}

// bij += sum_chunk u_part; c = softmax over i (axis 0). One block per o.
__global__ __launch_bounds__(256) void route_kernel(const float* __restrict__ u_part,
                                                    float* __restrict__ bij,
                                                    float* __restrict__ c,
                                                    int add_prev) {
  const int o = blockIdx.x;
  __shared__ float red[256];
  float val[5];
  float lmax = -1e30f;
#pragma unroll
  for (int k = 0; k < 5; ++k) {
    const int i = threadIdx.x + k * 256;
    if (i < IC) {
      float sacc = add_prev ? bij[i * OD + o] : 0.f;
#pragma unroll
      for (int ch = 0; ch < NCB; ++ch) sacc += u_part[((size_t)ch * IC + i) * OD + o];
      val[k] = sacc;
      bij[i * OD + o] = sacc;
      lmax = fmaxf(lmax, sacc);
    } else {
      val[k] = -1e30f;
    }
  }
  red[threadIdx.x] = lmax;
  __syncthreads();
  for (int st = 128; st > 0; st >>= 1) {
    if (threadIdx.x < st) red[threadIdx.x] = fmaxf(red[threadIdx.x], red[threadIdx.x + st]);
    __syncthreads();
  }
  const float gmax = red[0];
  __syncthreads();
  float lsum = 0.f;
#pragma unroll
  for (int k = 0; k < 5; ++k) {
    const int i = threadIdx.x + k * 256;
    if (i < IC) {
      val[k] = __expf(val[k] - gmax);
      lsum += val[k];
    }
  }
  red[threadIdx.x] = lsum;
  __syncthreads();
  for (int st = 128; st > 0; st >>= 1) {
    if (threadIdx.x < st) red[threadIdx.x] += red[threadIdx.x + st];
    __syncthreads();
  }
  const float inv = 1.f / red[0];
#pragma unroll
  for (int k = 0; k < 5; ++k) {
    const int i = threadIdx.x + k * 256;
    if (i < IC) c[i * OD + o] = val[k] * inv;
  }
}

extern "C" void kernel_launch(void* const* d_in, const int* in_sizes, int n_in,
                              void* d_out, int out_size, void* d_ws, size_t ws_size,
                              hipStream_t stream) {
  const float* x = (const float*)d_in[0];  // [512,1152,8] fp32
  const float* W = (const float*)d_in[1];  // [1152,10,16,8] fp32
  float* out = (float*)d_out;              // [512,10,16] fp32

  // workspace (fp32), 12.2 MB (< 12.58 MB footprint proven in R1/R2).
  // u_part aliases s_part (disjoint lifetimes: s_part dead after squash).
  float* ws = (float*)d_ws;
  float* s_part = ws;                      // NCS * 81920 = 2,949,120
  float* u_part = ws;                      // NCB * 11520 (alias)
  float* v = s_part + (size_t)NCS * SOP;   // 81920
  float* bij = v + SOP;                    // 11520
  float* c = bij + IC * OD;                // 11520

  const dim3 sgrid(B / 64, 4, NCS), sblk(64, 5);
  const dim3 agrid(IC / 8, NCB), ablk(64, 5);

  init_c_kernel<<<(IC * OD + 255) / 256, 256, 0, stream>>>(c);
  for (int iter = 0; iter < 3; ++iter) {
    s_kernel<<<sgrid, sblk, 0, stream>>>(x, W, c, s_part);
    squash_kernel<<<SOP / 256, 256, 0, stream>>>(s_part, v, out, iter == 2);
    if (iter < 2) {
      agree_kernel<<<agrid, ablk, 0, stream>>>(x, W, v, u_part);
      route_kernel<<<OD, 256, 0, stream>>>(u_part, bij, c, iter > 0);
    }
  }
}

// Round 7
// 213.262 us; speedup vs baseline: 2.0634x; 1.9012x over previous
//
#include <hip/hip_runtime.h>
#include <hip/hip_bf16.h>

// DigitCaps dynamic routing. Output fp32.
// R7: s-step as bf16 MFMA GEMM (M=512 b, N=160 o*16+p, K=9216 i*8+q, fp32 acc).
//  - build_b pre-swizzles Bs[kb][n][quad][j] = bf16(c[i,o]*W[i,o,p,q]) with
//    i=kb*4+quad, q=j  ->  every B-frag is a contiguous 1KB wave load.
//  - A-frags: per-lane direct fp32 x loads (A[m=lane&15][k=quad*8+j]) + RNE
//    pack to bf16 in registers. No LDS, no barriers in the GEMM.
// agree/route/squash kept from R6 (squash now reduces 16 partials).
#define B 512
#define IC 1152
#define QD 8
#define OD 10
#define PD 16
#define KD (IC * QD)      // 9216
#define NKB (KD / 32)     // 288 K32 blocks
#define NCS 16            // K-chunks for s GEMM; 288/16 = 18 K-steps per chunk
#define KSTEPS (NKB / NCS)
#define NCB 16            // b-chunks for agreement kernel
#define CSB (B / NCB)
#define SOP (B * OD * PD) // 81920

typedef short bf16x8 __attribute__((ext_vector_type(8)));
typedef float f32x4 __attribute__((ext_vector_type(4)));

__device__ __forceinline__ short f2bf(float f) {
  union { float f; unsigned u; } x;
  x.f = f;
  unsigned r = x.u + 0x7FFFu + ((x.u >> 16) & 1u);  // RNE to bf16
  return (short)(r >> 16);
}

// c = softmax of zero bij = uniform 1/1152
__global__ __launch_bounds__(256) void init_c_kernel(float* __restrict__ c) {
  const int t = blockIdx.x * 256 + threadIdx.x;
  if (t < IC * OD) c[t] = 1.0f / (float)IC;
}

// Bs[kb][n][quad][j] = bf16(c[i,o] * W[i,o,p,q]); i=kb*4+quad, q=j, n=o*16+p.
// thread per (kb,n): 288*160 = 46080 threads; writes 64B contiguous.
__global__ __launch_bounds__(256) void build_b_kernel(const float* __restrict__ W,
                                                      const float* __restrict__ c,
                                                      short* __restrict__ Bs) {
  const int t = blockIdx.x * 256 + threadIdx.x;
  if (t >= NKB * 160) return;
  const int kb = t / 160, n = t % 160;
  const int o = n >> 4, p = n & 15;
  short ov[32];
#pragma unroll
  for (int quad = 0; quad < 4; ++quad) {
    const int i = kb * 4 + quad;
    const float ci = c[i * OD + o];
    const float4* wp = (const float4*)(W + (((size_t)i * OD + o) * PD + p) * QD);
    const float4 w0 = wp[0], w1 = wp[1];
    ov[quad * 8 + 0] = f2bf(ci * w0.x);
    ov[quad * 8 + 1] = f2bf(ci * w0.y);
    ov[quad * 8 + 2] = f2bf(ci * w0.z);
    ov[quad * 8 + 3] = f2bf(ci * w0.w);
    ov[quad * 8 + 4] = f2bf(ci * w1.x);
    ov[quad * 8 + 5] = f2bf(ci * w1.y);
    ov[quad * 8 + 6] = f2bf(ci * w1.z);
    ov[quad * 8 + 7] = f2bf(ci * w1.w);
  }
  int4* dst = (int4*)(Bs + (size_t)t * 32);
  const int4* src = (const int4*)ov;
#pragma unroll
  for (int j = 0; j < 4; ++j) dst[j] = src[j];
}

// s_part[cz][b][n] partial GEMM. block=256 (4 waves, wave=16-row m-subtile),
// grid (8 m-blocks, 2 n-halves, NCS k-chunks). 5 MFMA chains per wave.
__global__ __launch_bounds__(256) void sgemm_kernel(const float* __restrict__ x,
                                                    const short* __restrict__ Bs,
                                                    float* __restrict__ s_part) {
  const int lane = threadIdx.x & 63;
  const int w = threadIdx.x >> 6;
  const int ln = lane & 15, quad = lane >> 4;
  const int m0 = blockIdx.x * 64 + w * 16;
  const int nb = blockIdx.y * 80;
  const int cz = blockIdx.z;
  f32x4 acc[5] = {};
  const float* arow = x + (size_t)(m0 + ln) * KD + quad * 8;
#pragma unroll 2
  for (int step = 0; step < KSTEPS; ++step) {
    const int kb = cz * KSTEPS + step;
    const float* ap = arow + kb * 32;
    const f32x4 a0 = *(const f32x4*)ap;
    const f32x4 a1 = *(const f32x4*)(ap + 4);
    bf16x8 af;
    af[0] = f2bf(a0[0]); af[1] = f2bf(a0[1]); af[2] = f2bf(a0[2]); af[3] = f2bf(a0[3]);
    af[4] = f2bf(a1[0]); af[5] = f2bf(a1[1]); af[6] = f2bf(a1[2]); af[7] = f2bf(a1[3]);
    const short* bp = Bs + (size_t)kb * 5120 + (nb + ln) * 32 + quad * 8;
#pragma unroll
    for (int nt = 0; nt < 5; ++nt) {
      const bf16x8 bf = *(const bf16x8*)(bp + nt * 512);  // nt*16 n-rows * 32
      acc[nt] = __builtin_amdgcn_mfma_f32_16x16x32_bf16(af, bf, acc[nt], 0, 0, 0);
    }
  }
  // C/D layout: col = lane&15, row = quad*4 + reg  [m89-verified]
  float* sp = s_part + (size_t)cz * SOP;
#pragma unroll
  for (int nt = 0; nt < 5; ++nt) {
#pragma unroll
    for (int r = 0; r < 4; ++r) {
      sp[(size_t)(m0 + quad * 4 + r) * 160 + nb + nt * 16 + ln] = acc[nt][r];
    }
  }
}

// reduce NCS partials (coalesced), squash per 16-lane p-group via shfl_xor.
__global__ __launch_bounds__(256) void squash_kernel(const float* __restrict__ s_part,
                                                     float* __restrict__ v,
                                                     float* __restrict__ out,
                                                     int write_out) {
  const int t = blockIdx.x * 256 + threadIdx.x;  // < 81920, layout (b*10+o)*16+p
  float sv = 0.f;
#pragma unroll
  for (int ch = 0; ch < NCS; ++ch) sv += s_part[(size_t)ch * SOP + t];
  float sq = sv * sv;
#pragma unroll
  for (int m = 1; m < 16; m <<= 1) sq += __shfl_xor(sq, m, 16);
  const float norm = sqrtf(sq + 1e-8f);
  const float val = sv * (sq / ((1.f + sq) * norm));
  v[t] = val;
  if (write_out) out[t] = val;
}

// u_part[chunk][i][o] = (1/B) sum_{b in chunk} sum_{q,p} W[i,o,p,q] x[b,i,q] v[b,o,p]
__global__ __launch_bounds__(320) void agree_kernel(const float* __restrict__ x,
                                                    const float* __restrict__ W,
                                                    const float* __restrict__ v,
                                                    float* __restrict__ u_part) {
  const int il = threadIdx.x >> 3;
  const int q = threadIdx.x & 7;
  const int i = blockIdx.x * 8 + il;
  const int b0 = blockIdx.y * CSB;
#pragma unroll
  for (int oo = 0; oo < 2; ++oo) {
    const int o = threadIdx.y + 5 * oo;  // wave-uniform
    float G[PD];
#pragma unroll
    for (int p = 0; p < PD; ++p) G[p] = 0.f;
    for (int b = b0; b < b0 + CSB; b += 2) {
      const float xa = x[((size_t)b * IC + i) * QD + q];
      const float xc = x[((size_t)(b + 1) * IC + i) * QD + q];
      const int vo0 = __builtin_amdgcn_readfirstlane((b * OD + o) * PD);
      const int vo1 = __builtin_amdgcn_readfirstlane(((b + 1) * OD + o) * PD);
      const float4* vp0 = (const float4*)(v + vo0);
      const float4* vp1 = (const float4*)(v + vo1);
      const float4 a0 = vp0[0], a1 = vp0[1], a2 = vp0[2], a3 = vp0[3];
      const float4 c0 = vp1[0], c1 = vp1[1], c2 = vp1[2], c3 = vp1[3];
      const float va[PD] = {a0.x, a0.y, a0.z, a0.w, a1.x, a1.y, a1.z, a1.w,
                            a2.x, a2.y, a2.z, a2.w, a3.x, a3.y, a3.z, a3.w};
      const float vc[PD] = {c0.x, c0.y, c0.z, c0.w, c1.x, c1.y, c1.z, c1.w,
                            c2.x, c2.y, c2.z, c2.w, c3.x, c3.y, c3.z, c3.w};
#pragma unroll
      for (int p = 0; p < PD; ++p) G[p] = fmaf(xa, va[p], G[p]);
#pragma unroll
      for (int p = 0; p < PD; ++p) G[p] = fmaf(xc, vc[p], G[p]);
    }
    const float* wq = W + ((size_t)(i * OD + o) * PD) * QD + q;
    float u = 0.f;
#pragma unroll
    for (int p = 0; p < PD; ++p) u = fmaf(wq[(size_t)p * QD], G[p], u);
    u += __shfl_xor(u, 1);
    u += __shfl_xor(u, 2);
    u += __shfl_xor(u, 4);
    if (q == 0) u_part[((size_t)blockIdx.y * IC + i) * OD + o] = u * (1.0f / (float)B);
  }
}

// bij += sum_chunk u_part; c = softmax over i (axis 0). One block per o.
__global__ __launch_bounds__(256) void route_kernel(const float* __restrict__ u_part,
                                                    float* __restrict__ bij,
                                                    float* __restrict__ c,
                                                    int add_prev) {
  const int o = blockIdx.x;
  __shared__ float red[256];
  float val[5];
  float lmax = -1e30f;
#pragma unroll
  for (int k = 0; k < 5; ++k) {
    const int i = threadIdx.x + k * 256;
    if (i < IC) {
      float sacc = add_prev ? bij[i * OD + o] : 0.f;
#pragma unroll
      for (int ch = 0; ch < NCB; ++ch) sacc += u_part[((size_t)ch * IC + i) * OD + o];
      val[k] = sacc;
      bij[i * OD + o] = sacc;
      lmax = fmaxf(lmax, sacc);
    } else {
      val[k] = -1e30f;
    }
  }
  red[threadIdx.x] = lmax;
  __syncthreads();
  for (int st = 128; st > 0; st >>= 1) {
    if (threadIdx.x < st) red[threadIdx.x] = fmaxf(red[threadIdx.x], red[threadIdx.x + st]);
    __syncthreads();
  }
  const float gmax = red[0];
  __syncthreads();
  float lsum = 0.f;
#pragma unroll
  for (int k = 0; k < 5; ++k) {
    const int i = threadIdx.x + k * 256;
    if (i < IC) {
      val[k] = __expf(val[k] - gmax);
      lsum += val[k];
    }
  }
  red[threadIdx.x] = lsum;
  __syncthreads();
  for (int st = 128; st > 0; st >>= 1) {
    if (threadIdx.x < st) red[threadIdx.x] += red[threadIdx.x + st];
    __syncthreads();
  }
  const float inv = 1.f / red[0];
#pragma unroll
  for (int k = 0; k < 5; ++k) {
    const int i = threadIdx.x + k * 256;
    if (i < IC) c[i * OD + o] = val[k] * inv;
  }
}

extern "C" void kernel_launch(void* const* d_in, const int* in_sizes, int n_in,
                              void* d_out, int out_size, void* d_ws, size_t ws_size,
                              hipStream_t stream) {
  const float* x = (const float*)d_in[0];  // [512,1152,8] fp32
  const float* W = (const float*)d_in[1];  // [1152,10,16,8] fp32
  float* out = (float*)d_out;              // [512,10,16] fp32

  // workspace: 2,890,240 float-slots = 11.56 MB (< 12.58 MB proven in R1/R2)
  float* ws = (float*)d_ws;
  float* s_part = ws;                         // NCS * 81920 = 1,310,720 floats
  float* v = s_part + (size_t)NCS * SOP;      // 81920
  float* bij = v + SOP;                       // 11520
  float* c = bij + IC * OD;                   // 11520
  short* Bs = (short*)(c + IC * OD);          // 288*160*32 shorts = 1,474,560 float-slots
  float* u_part = (float*)Bs;                 // 184,320 floats (alias; disjoint lifetime:
                                              // Bs dead after sgemm, u_part spans agree->route)

  const dim3 ggrid(8, 2, NCS), gblk(256);
  const dim3 agrid(IC / 8, NCB), ablk(64, 5);

  init_c_kernel<<<(IC * OD + 255) / 256, 256, 0, stream>>>(c);
  for (int iter = 0; iter < 3; ++iter) {
    build_b_kernel<<<(NKB * 160 + 255) / 256, 256, 0, stream>>>(W, c, Bs);
    sgemm_kernel<<<ggrid, gblk, 0, stream>>>(x, Bs, s_part);
    squash_kernel<<<SOP / 256, 256, 0, stream>>>(s_part, v, out, iter == 2);
    if (iter < 2) {
      agree_kernel<<<agrid, ablk, 0, stream>>>(x, W, v, u_part);
      route_kernel<<<OD, 256, 0, stream>>>(u_part, bij, c, iter > 0);
    }
  }
}

// Round 8
// 209.471 us; speedup vs baseline: 2.1008x; 1.0181x over previous
//
#include <hip/hip_runtime.h>
#include <hip/hip_bf16.h>

// DigitCaps dynamic routing. Output fp32.
// R8: (1) agree fuses both o-groups in one b-pass (x read once per dispatch,
// was twice); (2) sgemm split-K NCS 16->24 for 1.5 waves/SIMD. R7 established
// bf16-MFMA s-step with pre-swizzled B (absmax 4.9e-4, 6x margin).
#define B 512
#define IC 1152
#define QD 8
#define OD 10
#define PD 16
#define KD (IC * QD)      // 9216
#define NKB (KD / 32)     // 288 K32 blocks
#define NCS 24            // K-chunks for s GEMM; 288/24 = 12 K-steps per chunk
#define KSTEPS (NKB / NCS)
#define NCB 16            // b-chunks for agreement kernel
#define CSB (B / NCB)
#define SOP (B * OD * PD) // 81920

typedef short bf16x8 __attribute__((ext_vector_type(8)));
typedef float f32x4 __attribute__((ext_vector_type(4)));

__device__ __forceinline__ short f2bf(float f) {
  union { float f; unsigned u; } x;
  x.f = f;
  unsigned r = x.u + 0x7FFFu + ((x.u >> 16) & 1u);  // RNE to bf16
  return (short)(r >> 16);
}

// c = softmax of zero bij = uniform 1/1152
__global__ __launch_bounds__(256) void init_c_kernel(float* __restrict__ c) {
  const int t = blockIdx.x * 256 + threadIdx.x;
  if (t < IC * OD) c[t] = 1.0f / (float)IC;
}

// Bs[kb][n][quad][j] = bf16(c[i,o] * W[i,o,p,q]); i=kb*4+quad, q=j, n=o*16+p.
__global__ __launch_bounds__(256) void build_b_kernel(const float* __restrict__ W,
                                                      const float* __restrict__ c,
                                                      short* __restrict__ Bs) {
  const int t = blockIdx.x * 256 + threadIdx.x;
  if (t >= NKB * 160) return;
  const int kb = t / 160, n = t % 160;
  const int o = n >> 4, p = n & 15;
  short ov[32];
#pragma unroll
  for (int quad = 0; quad < 4; ++quad) {
    const int i = kb * 4 + quad;
    const float ci = c[i * OD + o];
    const float4* wp = (const float4*)(W + (((size_t)i * OD + o) * PD + p) * QD);
    const float4 w0 = wp[0], w1 = wp[1];
    ov[quad * 8 + 0] = f2bf(ci * w0.x);
    ov[quad * 8 + 1] = f2bf(ci * w0.y);
    ov[quad * 8 + 2] = f2bf(ci * w0.z);
    ov[quad * 8 + 3] = f2bf(ci * w0.w);
    ov[quad * 8 + 4] = f2bf(ci * w1.x);
    ov[quad * 8 + 5] = f2bf(ci * w1.y);
    ov[quad * 8 + 6] = f2bf(ci * w1.z);
    ov[quad * 8 + 7] = f2bf(ci * w1.w);
  }
  int4* dst = (int4*)(Bs + (size_t)t * 32);
  const int4* src = (const int4*)ov;
#pragma unroll
  for (int j = 0; j < 4; ++j) dst[j] = src[j];
}

// s_part[cz][b][n] partial GEMM. block=256 (4 waves, wave=16-row m-subtile),
// grid (8 m-blocks, 2 n-halves, NCS k-chunks). 5 MFMA chains per wave.
__global__ __launch_bounds__(256) void sgemm_kernel(const float* __restrict__ x,
                                                    const short* __restrict__ Bs,
                                                    float* __restrict__ s_part) {
  const int lane = threadIdx.x & 63;
  const int w = threadIdx.x >> 6;
  const int ln = lane & 15, quad = lane >> 4;
  const int m0 = blockIdx.x * 64 + w * 16;
  const int nb = blockIdx.y * 80;
  const int cz = blockIdx.z;
  f32x4 acc[5] = {};
  const float* arow = x + (size_t)(m0 + ln) * KD + quad * 8;
#pragma unroll 2
  for (int step = 0; step < KSTEPS; ++step) {
    const int kb = cz * KSTEPS + step;
    const float* ap = arow + kb * 32;
    const f32x4 a0 = *(const f32x4*)ap;
    const f32x4 a1 = *(const f32x4*)(ap + 4);
    bf16x8 af;
    af[0] = f2bf(a0[0]); af[1] = f2bf(a0[1]); af[2] = f2bf(a0[2]); af[3] = f2bf(a0[3]);
    af[4] = f2bf(a1[0]); af[5] = f2bf(a1[1]); af[6] = f2bf(a1[2]); af[7] = f2bf(a1[3]);
    const short* bp = Bs + (size_t)kb * 5120 + (nb + ln) * 32 + quad * 8;
#pragma unroll
    for (int nt = 0; nt < 5; ++nt) {
      const bf16x8 bf = *(const bf16x8*)(bp + nt * 512);
      acc[nt] = __builtin_amdgcn_mfma_f32_16x16x32_bf16(af, bf, acc[nt], 0, 0, 0);
    }
  }
  // C/D layout: col = lane&15, row = quad*4 + reg  [m89-verified]
  float* sp = s_part + (size_t)cz * SOP;
#pragma unroll
  for (int nt = 0; nt < 5; ++nt) {
#pragma unroll
    for (int r = 0; r < 4; ++r) {
      sp[(size_t)(m0 + quad * 4 + r) * 160 + nb + nt * 16 + ln] = acc[nt][r];
    }
  }
}

// reduce NCS partials (coalesced), squash per 16-lane p-group via shfl_xor.
__global__ __launch_bounds__(256) void squash_kernel(const float* __restrict__ s_part,
                                                     float* __restrict__ v,
                                                     float* __restrict__ out,
                                                     int write_out) {
  const int t = blockIdx.x * 256 + threadIdx.x;  // < 81920, layout (b*10+o)*16+p
  float sv = 0.f;
#pragma unroll
  for (int ch = 0; ch < NCS; ++ch) sv += s_part[(size_t)ch * SOP + t];
  float sq = sv * sv;
#pragma unroll
  for (int m = 1; m < 16; m <<= 1) sq += __shfl_xor(sq, m, 16);
  const float norm = sqrtf(sq + 1e-8f);
  const float val = sv * (sq / ((1.f + sq) * norm));
  v[t] = val;
  if (write_out) out[t] = val;
}

// u_part[chunk][i][o] = (1/B) sum_{b in chunk} sum_{q,p} W[i,o,p,q] x[b,i,q] v[b,o,p]
// lane=(i_local<<3)|q; block (64,5); BOTH o-groups accumulated in one b-pass.
__global__ __launch_bounds__(320) void agree_kernel(const float* __restrict__ x,
                                                    const float* __restrict__ W,
                                                    const float* __restrict__ v,
                                                    float* __restrict__ u_part) {
  const int il = threadIdx.x >> 3;
  const int q = threadIdx.x & 7;
  const int i = blockIdx.x * 8 + il;
  const int b0 = blockIdx.y * CSB;
  const int o1 = threadIdx.y;       // wave-uniform
  const int o2 = threadIdx.y + 5;
  float G0[PD], G1[PD];
#pragma unroll
  for (int p = 0; p < PD; ++p) { G0[p] = 0.f; G1[p] = 0.f; }
  for (int b = b0; b < b0 + CSB; ++b) {
    const float xa = x[((size_t)b * IC + i) * QD + q];  // coalesced 256B wave-load
    const int vo0 = __builtin_amdgcn_readfirstlane((b * OD + o1) * PD);
    const int vo1 = __builtin_amdgcn_readfirstlane((b * OD + o2) * PD);
    const float4* vp0 = (const float4*)(v + vo0);
    const float4* vp1 = (const float4*)(v + vo1);
    const float4 a0 = vp0[0], a1 = vp0[1], a2 = vp0[2], a3 = vp0[3];
    const float4 c0 = vp1[0], c1 = vp1[1], c2 = vp1[2], c3 = vp1[3];
    const float va[PD] = {a0.x, a0.y, a0.z, a0.w, a1.x, a1.y, a1.z, a1.w,
                          a2.x, a2.y, a2.z, a2.w, a3.x, a3.y, a3.z, a3.w};
    const float vc[PD] = {c0.x, c0.y, c0.z, c0.w, c1.x, c1.y, c1.z, c1.w,
                          c2.x, c2.y, c2.z, c2.w, c3.x, c3.y, c3.z, c3.w};
#pragma unroll
    for (int p = 0; p < PD; ++p) G0[p] = fmaf(xa, va[p], G0[p]);
#pragma unroll
    for (int p = 0; p < PD; ++p) G1[p] = fmaf(xa, vc[p], G1[p]);
  }
  const float* wq1 = W + ((size_t)(i * OD + o1) * PD) * QD + q;
  const float* wq2 = W + ((size_t)(i * OD + o2) * PD) * QD + q;
  float u0 = 0.f, u1 = 0.f;
#pragma unroll
  for (int p = 0; p < PD; ++p) {
    u0 = fmaf(wq1[(size_t)p * QD], G0[p], u0);
    u1 = fmaf(wq2[(size_t)p * QD], G1[p], u1);
  }
  u0 += __shfl_xor(u0, 1); u0 += __shfl_xor(u0, 2); u0 += __shfl_xor(u0, 4);
  u1 += __shfl_xor(u1, 1); u1 += __shfl_xor(u1, 2); u1 += __shfl_xor(u1, 4);
  if (q == 0) {
    float* up = u_part + ((size_t)blockIdx.y * IC + i) * OD;
    up[o1] = u0 * (1.0f / (float)B);
    up[o2] = u1 * (1.0f / (float)B);
  }
}

// bij += sum_chunk u_part; c = softmax over i (axis 0). One block per o.
__global__ __launch_bounds__(256) void route_kernel(const float* __restrict__ u_part,
                                                    float* __restrict__ bij,
                                                    float* __restrict__ c,
                                                    int add_prev) {
  const int o = blockIdx.x;
  __shared__ float red[256];
  float val[5];
  float lmax = -1e30f;
#pragma unroll
  for (int k = 0; k < 5; ++k) {
    const int i = threadIdx.x + k * 256;
    if (i < IC) {
      float sacc = add_prev ? bij[i * OD + o] : 0.f;
#pragma unroll
      for (int ch = 0; ch < NCB; ++ch) sacc += u_part[((size_t)ch * IC + i) * OD + o];
      val[k] = sacc;
      bij[i * OD + o] = sacc;
      lmax = fmaxf(lmax, sacc);
    } else {
      val[k] = -1e30f;
    }
  }
  red[threadIdx.x] = lmax;
  __syncthreads();
  for (int st = 128; st > 0; st >>= 1) {
    if (threadIdx.x < st) red[threadIdx.x] = fmaxf(red[threadIdx.x], red[threadIdx.x + st]);
    __syncthreads();
  }
  const float gmax = red[0];
  __syncthreads();
  float lsum = 0.f;
#pragma unroll
  for (int k = 0; k < 5; ++k) {
    const int i = threadIdx.x + k * 256;
    if (i < IC) {
      val[k] = __expf(val[k] - gmax);
      lsum += val[k];
    }
  }
  red[threadIdx.x] = lsum;
  __syncthreads();
  for (int st = 128; st > 0; st >>= 1) {
    if (threadIdx.x < st) red[threadIdx.x] += red[threadIdx.x + st];
    __syncthreads();
  }
  const float inv = 1.f / red[0];
#pragma unroll
  for (int k = 0; k < 5; ++k) {
    const int i = threadIdx.x + k * 256;
    if (i < IC) c[i * OD + o] = val[k] * inv;
  }
}

extern "C" void kernel_launch(void* const* d_in, const int* in_sizes, int n_in,
                              void* d_out, int out_size, void* d_ws, size_t ws_size,
                              hipStream_t stream) {
  const float* x = (const float*)d_in[0];  // [512,1152,8] fp32
  const float* W = (const float*)d_in[1];  // [1152,10,16,8] fp32
  float* out = (float*)d_out;              // [512,10,16] fp32

  // workspace: s_part 24*81920 + v + bij + c = 2,071,040 floats, then Bs
  // 1,474,560 shorts (= 737,280 float-slots). Total 2,808,320 f-slots = 11.23 MB
  // (< 12.58 MB proven in R1/R2). u_part aliases Bs (disjoint lifetimes).
  float* ws = (float*)d_ws;
  float* s_part = ws;                         // NCS * 81920
  float* v = s_part + (size_t)NCS * SOP;      // 81920
  float* bij = v + SOP;                       // 11520
  float* c = bij + IC * OD;                   // 11520
  short* Bs = (short*)(c + IC * OD);          // 288*160*32 shorts
  float* u_part = (float*)Bs;                 // 184,320 floats (alias)

  const dim3 ggrid(8, 2, NCS), gblk(256);
  const dim3 agrid(IC / 8, NCB), ablk(64, 5);

  init_c_kernel<<<(IC * OD + 255) / 256, 256, 0, stream>>>(c);
  for (int iter = 0; iter < 3; ++iter) {
    build_b_kernel<<<(NKB * 160 + 255) / 256, 256, 0, stream>>>(W, c, Bs);
    sgemm_kernel<<<ggrid, gblk, 0, stream>>>(x, Bs, s_part);
    squash_kernel<<<SOP / 256, 256, 0, stream>>>(s_part, v, out, iter == 2);
    if (iter < 2) {
      agree_kernel<<<agrid, ablk, 0, stream>>>(x, W, v, u_part);
      route_kernel<<<OD, 256, 0, stream>>>(u_part, bij, c, iter > 0);
    }
  }
}